// Round 9
// baseline (404.263 us; speedup 1.0000x reference)
//
#include <hip/hip_runtime.h>
#include <hip/hip_bf16.h>

#ifndef MIN
#define MIN(a,b) ((a)<(b)?(a):(b))
#endif

typedef _Float16 half2_t __attribute__((ext_vector_type(2)));
typedef _Float16 half4_t __attribute__((ext_vector_type(4)));
typedef _Float16 half8_t __attribute__((ext_vector_type(8)));
typedef float floatx4 __attribute__((ext_vector_type(4)));

#define BUCKET_SHIFT 6
#define BUCKET_SIZE 64
#define SCHUNK 8192
#define WPAD 132   // 128 + 4 halves: row stride 66 dwords -> 2-way LDS conflict (free)

// ---------------------------------------------------------------------------
// Bucketed CSR build (counting sort by dst, 64-node buckets)
// rec packing: src in bits 0..15 (N<=65536), dst&63 in bits 16..21.
// ---------------------------------------------------------------------------

__global__ void hist_kernel(const int* __restrict__ dst, int E,
                            int* __restrict__ bucketCnt, int NB) {
    __shared__ int h[1024];
    int t = threadIdx.x;
    for (int i = t; i < 1024; i += 256) h[i] = 0;
    __syncthreads();
    for (int e = blockIdx.x * 256 + t; e < E; e += gridDim.x * 256)
        atomicAdd(&h[dst[e] >> BUCKET_SHIFT], 1);
    __syncthreads();
    for (int i = t; i < NB; i += 256)
        if (h[i]) atomicAdd(&bucketCnt[i], h[i]);   // no return use -> pipelined
}

__global__ void bucket_scan(const int* __restrict__ bucketCnt,
                            int* __restrict__ bucketBase, int* __restrict__ bucketCur,
                            int NB, int E) {
    __shared__ int sm[1024];
    int t = threadIdx.x;
    int v = (t < NB) ? bucketCnt[t] : 0;
    sm[t] = v;
    __syncthreads();
    for (int off = 1; off < 1024; off <<= 1) {
        int add = (t >= off) ? sm[t - off] : 0;
        __syncthreads();
        sm[t] += add;
        __syncthreads();
    }
    if (t < NB) {
        bucketBase[t] = sm[t] - v;
        bucketCur[t] = sm[t] - v;
    }
    if (t == 0) bucketBase[NB] = E;
}

// Two-level scatter: per-chunk LDS histogram, one returning atomic per
// (block,bucket), then contiguous placement via LDS cursors.
__global__ void scatter_kernel(const int* __restrict__ src, const int* __restrict__ dst,
                               int E, int* __restrict__ bucketCur, unsigned* __restrict__ rec) {
    __shared__ int hist[1024];
    __shared__ int base[1024];
    int t = threadIdx.x;
    int e0 = blockIdx.x * SCHUNK;
    int e1 = MIN(E, e0 + SCHUNK);
    for (int i = t; i < 1024; i += 256) hist[i] = 0;
    __syncthreads();
    for (int e = e0 + t; e < e1; e += 256)
        atomicAdd(&hist[dst[e] >> BUCKET_SHIFT], 1);
    __syncthreads();
    for (int i = t; i < 1024; i += 256) {
        int c = hist[i];
        base[i] = c ? atomicAdd(&bucketCur[i], c) : 0;
        hist[i] = 0;                                      // reuse as local cursor
    }
    __syncthreads();
    for (int e = e0 + t; e < e1; e += 256) {
        int d = dst[e];
        int b = d >> BUCKET_SHIFT;
        int pos = base[b] + atomicAdd(&hist[b], 1);       // LDS atomic, cheap
        rec[pos] = (unsigned)src[e] | ((unsigned)(d & (BUCKET_SIZE - 1)) << 16);
    }
}

__global__ void bucket_build(const unsigned* __restrict__ rec, const int* __restrict__ bucketBase,
                             int* __restrict__ rowptr, int* __restrict__ csr_src,
                             float* __restrict__ dinv, int N, int E) {
    __shared__ int lcnt[256];
    __shared__ int sm[256];
    __shared__ int lcur[64];
    int b = blockIdx.x;
    int t = threadIdx.x;
    int beg = bucketBase[b], end = bucketBase[b + 1];
    lcnt[t] = 0;
    __syncthreads();
    for (int i = beg + t; i < end; i += 256)
        atomicAdd(&lcnt[rec[i] >> 16], 1);
    __syncthreads();
    int v = lcnt[t];
    sm[t] = v;
    __syncthreads();
    for (int off = 1; off < 256; off <<= 1) {
        int add = (t >= off) ? sm[t - off] : 0;
        __syncthreads();
        sm[t] += add;
        __syncthreads();
    }
    int excl = sm[t] - v;
    if (t < BUCKET_SIZE) {
        int node = b * BUCKET_SIZE + t;
        if (node < N) {
            rowptr[node] = beg + excl;
            dinv[node] = rsqrtf((float)(v + 1));   // self loop -> deg >= 1
        }
        lcur[t] = beg + excl;
    }
    __syncthreads();
    for (int i = beg + t; i < end; i += 256) {
        unsigned r = rec[i];
        int pos = atomicAdd(&lcur[r >> 16], 1);
        csr_src[pos] = (int)(r & 0xFFFFu);
    }
    if (b == 0 && t == 0) rowptr[N] = E;
}

// ---------------------------------------------------------------------------
// Aggregation over f16 H (half4 = 8B/lane, 2 edges per gather instruction):
// X[node] = relu( di*( di*H[node] + sum dinv[s]*H[s] ) )
// 1 wave per node; lanes 0-31 = even edges, 32-63 = odd edges; shfl_xor(32)
// cross-half reduce at the end. 8 independent 2-edge gathers in flight.
// ---------------------------------------------------------------------------

__global__ void agg_kernel(const half4_t* __restrict__ H4, const float* __restrict__ dinv,
                           const int* __restrict__ rowptr, const int* __restrict__ csr_src,
                           half4_t* __restrict__ X4, int N) {
    int node = blockIdx.x * 4 + (threadIdx.x >> 6);
    int t = threadIdx.x & 63;
    int half = t >> 5;
    int c = t & 31;             // channel group: ch 4c..4c+3
    if (node >= N) return;
    float di = dinv[node];
    float4 acc = {0.f, 0.f, 0.f, 0.f};
    if (half == 0) {            // self term once; reduce propagates it
        half4_t h = H4[(size_t)node * 32 + c];
        acc.x = (float)h.x * di; acc.y = (float)h.y * di;
        acc.z = (float)h.z * di; acc.w = (float)h.w * di;
    }
    int beg = rowptr[node];
    int end = rowptr[node + 1];

    for (int base = beg; base < end; base += 64) {
        int idx = base + t;
        bool valid = idx < end;
        int s_lane = valid ? csr_src[idx] : node;    // safe address for pads
        float w_lane = valid ? dinv[s_lane] : 0.0f;  // zero weight for pads
        int m = end - base;
        if (m > 64) m = 64;
        int mm = (m + 15) & ~15;                     // 16 edges per inner iter
        for (int j = 0; j < mm; j += 16) {
            half4_t u[8];
            float w[8];
#pragma unroll
            for (int k = 0; k < 8; ++k) {
                int e = j + 2 * k + half;
                int s = __shfl(s_lane, e);
                w[k] = __shfl(w_lane, e);
                u[k] = H4[(size_t)s * 32 + c];
            }
#pragma unroll
            for (int k = 0; k < 8; ++k) {
                acc.x = fmaf((float)u[k].x, w[k], acc.x);
                acc.y = fmaf((float)u[k].y, w[k], acc.y);
                acc.z = fmaf((float)u[k].z, w[k], acc.z);
                acc.w = fmaf((float)u[k].w, w[k], acc.w);
            }
        }
    }
    acc.x += __shfl_xor(acc.x, 32);
    acc.y += __shfl_xor(acc.y, 32);
    acc.z += __shfl_xor(acc.z, 32);
    acc.w += __shfl_xor(acc.w, 32);
    if (half == 0) {
        half4_t o;
        o.x = (_Float16)fmaxf(acc.x * di, 0.0f);
        o.y = (_Float16)fmaxf(acc.y * di, 0.0f);
        o.z = (_Float16)fmaxf(acc.z * di, 0.0f);
        o.w = (_Float16)fmaxf(acc.w * di, 0.0f);
        X4[(size_t)node * 32 + c] = o;
    }
}

// ---------------------------------------------------------------------------
// MFMA f16 GEMM, K=128, BM=64, 256 threads (4 waves). W staged fp32->f16 in
// LDS; A-fragments loaded directly from global.
// A: lane reads A[m=lane&15][k=(lane>>4)*8+ks*32 ..+7]; C/D: col=lane&15,
// row=(lane>>4)*4+reg.
// ---------------------------------------------------------------------------

template <int BN, bool A_F16, bool RELU, bool BIAS, bool ACCUM, bool F16OUT>
__global__ __launch_bounds__(256)
void mfma_gemm(const void* __restrict__ Av,
               const float* __restrict__ W, int ldw,
               const float* __restrict__ bias,
               void* __restrict__ Cv, int ldc, int M) {
    constexpr int NT = BN / 16;
    __shared__ __align__(16) _Float16 Ws[BN][WPAD];

    int tid = threadIdx.x;
    int rowBase = blockIdx.x * 64;

#pragma unroll
    for (int i = tid; i < BN * 32; i += 256) {
        int n = i >> 5, c4 = (i & 31) * 4;
        float4 v = *(const float4*)(W + (size_t)n * ldw + c4);
        half4_t h = {(_Float16)v.x, (_Float16)v.y, (_Float16)v.z, (_Float16)v.w};
        *(half4_t*)(&Ws[n][c4]) = h;
    }
    __syncthreads();

    int w = tid >> 6;
    int lane = tid & 63;
    int lrow = lane & 15;
    int quad = lane >> 4;
    int kq = quad * 8;
    int grow = rowBase + w * 16 + lrow;
    bool rok = grow < M;

    floatx4 acc[NT];
#pragma unroll
    for (int nt = 0; nt < NT; ++nt) acc[nt] = (floatx4){0.f, 0.f, 0.f, 0.f};

#pragma unroll
    for (int ks = 0; ks < 4; ++ks) {
        int kk = ks * 32 + kq;
        half8_t a = {0, 0, 0, 0, 0, 0, 0, 0};
        if (rok) {
            if (A_F16) {
                a = *(const half8_t*)((const _Float16*)Av + (size_t)grow * 128 + kk);
            } else {
                const float* A = (const float*)Av;
                float4 v0 = *(const float4*)(A + (size_t)grow * 128 + kk);
                float4 v1 = *(const float4*)(A + (size_t)grow * 128 + kk + 4);
                a = (half8_t){(_Float16)v0.x, (_Float16)v0.y, (_Float16)v0.z, (_Float16)v0.w,
                              (_Float16)v1.x, (_Float16)v1.y, (_Float16)v1.z, (_Float16)v1.w};
            }
        }
#pragma unroll
        for (int nt = 0; nt < NT; ++nt) {
            half8_t b = *(const half8_t*)(&Ws[nt * 16 + lrow][kk]);
            acc[nt] = __builtin_amdgcn_mfma_f32_16x16x32_f16(a, b, acc[nt], 0, 0, 0);
        }
    }

#pragma unroll
    for (int nt = 0; nt < NT; ++nt) {
        int col = nt * 16 + lrow;
        float bv = BIAS ? bias[col] : 0.0f;
#pragma unroll
        for (int reg = 0; reg < 4; ++reg) {
            int gr = rowBase + w * 16 + quad * 4 + reg;
            if (gr < M) {
                float v = acc[nt][reg] + bv;
                if (RELU) v = fmaxf(v, 0.0f);
                if (F16OUT) {
                    _Float16* C = (_Float16*)Cv;
                    C[(size_t)gr * ldc + col] = (_Float16)v;
                } else {
                    float* C = (float*)Cv;
                    if (ACCUM) v += C[(size_t)gr * ldc + col];
                    C[(size_t)gr * ldc + col] = v;
                }
            }
        }
    }
}

// ---------------------------------------------------------------------------
// Fused input-proj + conv0:  X1 = relu(x @ W_in^T + b_in)  (LDS only),
//                            H0 = X1 @ Wc0^T + bc0         (f16 global)
// ---------------------------------------------------------------------------

__global__ __launch_bounds__(256)
void input_conv_fused(const float* __restrict__ x,
                      const float* __restrict__ W_in, const float* __restrict__ b_in,
                      const float* __restrict__ Wc0, const float* __restrict__ bc0,
                      _Float16* __restrict__ H, int M) {
    __shared__ __align__(16) _Float16 Ws[128][WPAD];
    __shared__ __align__(16) _Float16 As[64][WPAD];

    int tid = threadIdx.x;
    int rowBase = blockIdx.x * 64;
    int w = tid >> 6;
    int lane = tid & 63;
    int lrow = lane & 15;
    int quad = lane >> 4;
    int kq = quad * 8;
    int grow = rowBase + w * 16 + lrow;
    bool rok = grow < M;

    // ---- stage W_in ----
#pragma unroll
    for (int i = tid; i < 128 * 32; i += 256) {
        int n = i >> 5, c4 = (i & 31) * 4;
        float4 v = *(const float4*)(W_in + (size_t)n * 128 + c4);
        half4_t h = {(_Float16)v.x, (_Float16)v.y, (_Float16)v.z, (_Float16)v.w};
        *(half4_t*)(&Ws[n][c4]) = h;
    }
    __syncthreads();

    // ---- GEMM 1: x @ W_in^T ----
    floatx4 acc[8];
#pragma unroll
    for (int nt = 0; nt < 8; ++nt) acc[nt] = (floatx4){0.f, 0.f, 0.f, 0.f};
#pragma unroll
    for (int ks = 0; ks < 4; ++ks) {
        int kk = ks * 32 + kq;
        half8_t a = {0, 0, 0, 0, 0, 0, 0, 0};
        if (rok) {
            float4 v0 = *(const float4*)(x + (size_t)grow * 128 + kk);
            float4 v1 = *(const float4*)(x + (size_t)grow * 128 + kk + 4);
            a = (half8_t){(_Float16)v0.x, (_Float16)v0.y, (_Float16)v0.z, (_Float16)v0.w,
                          (_Float16)v1.x, (_Float16)v1.y, (_Float16)v1.z, (_Float16)v1.w};
        }
#pragma unroll
        for (int nt = 0; nt < 8; ++nt) {
            half8_t b = *(const half8_t*)(&Ws[nt * 16 + lrow][kk]);
            acc[nt] = __builtin_amdgcn_mfma_f32_16x16x32_f16(a, b, acc[nt], 0, 0, 0);
        }
    }

    // ---- X1 = relu(. + b_in) -> LDS As ----
#pragma unroll
    for (int nt = 0; nt < 8; ++nt) {
        int col = nt * 16 + lrow;
        float bv = b_in[col];
#pragma unroll
        for (int reg = 0; reg < 4; ++reg) {
            int r = w * 16 + quad * 4 + reg;
            As[r][col] = (_Float16)fmaxf(acc[nt][reg] + bv, 0.0f);
        }
    }
    __syncthreads();

    // ---- restage Ws with Wc0 ----
#pragma unroll
    for (int i = tid; i < 128 * 32; i += 256) {
        int n = i >> 5, c4 = (i & 31) * 4;
        float4 v = *(const float4*)(Wc0 + (size_t)n * 128 + c4);
        half4_t h = {(_Float16)v.x, (_Float16)v.y, (_Float16)v.z, (_Float16)v.w};
        *(half4_t*)(&Ws[n][c4]) = h;
    }
    __syncthreads();

    // ---- GEMM 2: X1 @ Wc0^T ----
#pragma unroll
    for (int nt = 0; nt < 8; ++nt) acc[nt] = (floatx4){0.f, 0.f, 0.f, 0.f};
#pragma unroll
    for (int ks = 0; ks < 4; ++ks) {
        int kk = ks * 32 + kq;
        half8_t a = *(const half8_t*)(&As[w * 16 + lrow][kk]);
#pragma unroll
        for (int nt = 0; nt < 8; ++nt) {
            half8_t b = *(const half8_t*)(&Ws[nt * 16 + lrow][kk]);
            acc[nt] = __builtin_amdgcn_mfma_f32_16x16x32_f16(a, b, acc[nt], 0, 0, 0);
        }
    }
#pragma unroll
    for (int nt = 0; nt < 8; ++nt) {
        int col = nt * 16 + lrow;
        float bv = bc0[col];
#pragma unroll
        for (int reg = 0; reg < 4; ++reg) {
            int gr = rowBase + w * 16 + quad * 4 + reg;
            if (gr < M) H[(size_t)gr * 128 + col] = (_Float16)(acc[nt][reg] + bv);
        }
    }
}

// ---------------------------------------------------------------------------
// Fused conv-GEMM + out-slice GEMM: reads A (f16) once, computes
//   H[m][0..127]   = A @ W1^T + bc        (f16 out)
//   out[m][0..63] (+)= A @ W2^T (+b_out)  (fp32, FIRST: overwrite w/ bias)
// ---------------------------------------------------------------------------

template <bool FIRST>
__global__ __launch_bounds__(256)
void mfma_gemm_fused(const _Float16* __restrict__ A,
                     const float* __restrict__ W1,           // [128][128]
                     const float* __restrict__ bc,
                     _Float16* __restrict__ H,
                     const float* __restrict__ W2, int ldw2, // [64][ldw2] slice
                     const float* __restrict__ b_out,
                     float* __restrict__ out, int M) {
    __shared__ __align__(16) _Float16 Ws[192][WPAD];   // rows 0..127=W1, 128..191=W2

    int tid = threadIdx.x;
    int rowBase = blockIdx.x * 64;

#pragma unroll
    for (int i = tid; i < 128 * 32; i += 256) {
        int n = i >> 5, c4 = (i & 31) * 4;
        float4 v = *(const float4*)(W1 + (size_t)n * 128 + c4);
        half4_t h = {(_Float16)v.x, (_Float16)v.y, (_Float16)v.z, (_Float16)v.w};
        *(half4_t*)(&Ws[n][c4]) = h;
    }
#pragma unroll
    for (int i = tid; i < 64 * 32; i += 256) {
        int n = i >> 5, c4 = (i & 31) * 4;
        float4 v = *(const float4*)(W2 + (size_t)n * ldw2 + c4);
        half4_t h = {(_Float16)v.x, (_Float16)v.y, (_Float16)v.z, (_Float16)v.w};
        *(half4_t*)(&Ws[128 + n][c4]) = h;
    }
    __syncthreads();

    int w = tid >> 6;
    int lane = tid & 63;
    int lrow = lane & 15;
    int quad = lane >> 4;
    int kq = quad * 8;
    int grow = rowBase + w * 16 + lrow;
    bool rok = grow < M;

    floatx4 acc1[8], acc2[4];
#pragma unroll
    for (int nt = 0; nt < 8; ++nt) acc1[nt] = (floatx4){0.f, 0.f, 0.f, 0.f};
#pragma unroll
    for (int nt = 0; nt < 4; ++nt) acc2[nt] = (floatx4){0.f, 0.f, 0.f, 0.f};

#pragma unroll
    for (int ks = 0; ks < 4; ++ks) {
        int kk = ks * 32 + kq;
        half8_t a = {0, 0, 0, 0, 0, 0, 0, 0};
        if (rok) a = *(const half8_t*)(A + (size_t)grow * 128 + kk);
#pragma unroll
        for (int nt = 0; nt < 8; ++nt) {
            half8_t b = *(const half8_t*)(&Ws[nt * 16 + lrow][kk]);
            acc1[nt] = __builtin_amdgcn_mfma_f32_16x16x32_f16(a, b, acc1[nt], 0, 0, 0);
        }
#pragma unroll
        for (int nt = 0; nt < 4; ++nt) {
            half8_t b = *(const half8_t*)(&Ws[128 + nt * 16 + lrow][kk]);
            acc2[nt] = __builtin_amdgcn_mfma_f32_16x16x32_f16(a, b, acc2[nt], 0, 0, 0);
        }
    }

#pragma unroll
    for (int nt = 0; nt < 8; ++nt) {
        int col = nt * 16 + lrow;
        float bv = bc[col];
#pragma unroll
        for (int reg = 0; reg < 4; ++reg) {
            int gr = rowBase + w * 16 + quad * 4 + reg;
            if (gr < M) H[(size_t)gr * 128 + col] = (_Float16)(acc1[nt][reg] + bv);
        }
    }
#pragma unroll
    for (int nt = 0; nt < 4; ++nt) {
        int col = nt * 16 + lrow;
        float bv = FIRST ? b_out[col] : 0.0f;
#pragma unroll
        for (int reg = 0; reg < 4; ++reg) {
            int gr = rowBase + w * 16 + quad * 4 + reg;
            if (gr < M) {
                float v = acc2[nt][reg] + bv;
                if (!FIRST) v += out[(size_t)gr * 64 + col];
                out[(size_t)gr * 64 + col] = v;
            }
        }
    }
}

// ---------------------------------------------------------------------------
// launch
// ---------------------------------------------------------------------------

extern "C" void kernel_launch(void* const* d_in, const int* in_sizes, int n_in,
                              void* d_out, int out_size, void* d_ws, size_t ws_size,
                              hipStream_t stream) {
    const float* x     = (const float*)d_in[0];
    const int*   ei    = (const int*)d_in[1];
    const float* W_in  = (const float*)d_in[2];
    const float* b_in  = (const float*)d_in[3];
    const float* Wc    = (const float*)d_in[4];
    const float* bc    = (const float*)d_in[5];
    const float* W_out = (const float*)d_in[6];
    const float* b_out = (const float*)d_in[7];
    float* out = (float*)d_out;

    const int HID = 128;
    const int N = in_sizes[0] / HID;   // 50000
    const int E = in_sizes[1] / 2;     // 800000
    const int* src = ei;
    const int* dst = ei + E;
    const int NB = (N + BUCKET_SIZE - 1) >> BUCKET_SHIFT;   // 782

    char* ws = (char*)d_ws;
    size_t off = 0;
    auto carve = [&](size_t bytes) {
        void* p = ws + off;
        off += (bytes + 255) & ~(size_t)255;
        return p;
    };
    float* dinv      = (float*)carve((size_t)N * 4);
    int*   rowptr    = (int*)carve((size_t)(N + 1) * 4);
    int*   csr_src   = (int*)carve((size_t)E * 4);
    unsigned* rec    = (unsigned*)carve((size_t)E * 4);
    int*   bucketCnt = (int*)carve((size_t)1024 * 4);
    int*   bucketBase= (int*)carve((size_t)1025 * 4);
    int*   bucketCur = (int*)carve((size_t)1024 * 4);
    _Float16* bufA   = (_Float16*)carve((size_t)N * HID * 2);
    _Float16* bufH   = (_Float16*)carve((size_t)N * HID * 2);
    (void)ws_size;

    // ---- bucketed CSR + norm build ----
    hipMemsetAsync(bucketCnt, 0, (size_t)1024 * 4, stream);
    hist_kernel<<<512, 256, 0, stream>>>(dst, E, bucketCnt, NB);
    bucket_scan<<<1, 1024, 0, stream>>>(bucketCnt, bucketBase, bucketCur, NB, E);
    scatter_kernel<<<(E + SCHUNK - 1) / SCHUNK, 256, 0, stream>>>(src, dst, E, bucketCur, rec);
    bucket_build<<<NB, 256, 0, stream>>>(rec, bucketBase, rowptr, csr_src, dinv, N, E);

    int gemm_blocks = (N + 63) / 64;
    dim3 agg_grid((N + 3) / 4);

    // ---- fused input-proj + conv0: bufH = (relu(x@W_in^T+b_in)) @ Wc0^T + bc0 ----
    input_conv_fused<<<gemm_blocks, 256, 0, stream>>>(x, W_in, b_in, Wc, bc, bufH, N);
    agg_kernel<<<agg_grid, 256, 0, stream>>>((const half4_t*)bufH, dinv, rowptr,
                                             csr_src, (half4_t*)bufA, N);

    // ---- layers 1..3: fused [conv_l | out-slice_{l-1}] then agg ----
    for (int l = 1; l < 4; ++l) {
        if (l == 1) {
            mfma_gemm_fused<true><<<gemm_blocks, 256, 0, stream>>>(
                bufA, Wc + (size_t)l * HID * HID, bc + (size_t)l * HID, bufH,
                W_out + (size_t)(l - 1) * HID, 512, b_out, out, N);
        } else {
            mfma_gemm_fused<false><<<gemm_blocks, 256, 0, stream>>>(
                bufA, Wc + (size_t)l * HID * HID, bc + (size_t)l * HID, bufH,
                W_out + (size_t)(l - 1) * HID, 512, nullptr, out, N);
        }
        agg_kernel<<<agg_grid, 256, 0, stream>>>((const half4_t*)bufH, dinv, rowptr,
                                                 csr_src, (half4_t*)bufA, N);
    }

    // ---- final out slice (l=3): out += bufA @ W_out[:, 384:512]^T ----
    mfma_gemm<64, true, false, false, true, false>
        <<<gemm_blocks, 256, 0, stream>>>(bufA, W_out + (size_t)3 * HID, 512,
                                          nullptr, out, 64, N);
}

// Round 10
// 396.289 us; speedup vs baseline: 1.0201x; 1.0201x over previous
//
#include <hip/hip_runtime.h>
#include <hip/hip_bf16.h>

#ifndef MIN
#define MIN(a,b) ((a)<(b)?(a):(b))
#endif

typedef _Float16 half2_t __attribute__((ext_vector_type(2)));
typedef _Float16 half4_t __attribute__((ext_vector_type(4)));
typedef _Float16 half8_t __attribute__((ext_vector_type(8)));
typedef float floatx4 __attribute__((ext_vector_type(4)));

#define BUCKET_SHIFT 6
#define BUCKET_SIZE 64
#define SCHUNK 8192
#define WPAD 132   // 128 + 4 halves: row stride 66 dwords -> 2-way LDS conflict (free)

// ---------------------------------------------------------------------------
// Bucketed CSR build (counting sort by dst, 64-node buckets)
// rec packing: src in bits 0..15 (N<=65536), dst&63 in bits 16..21.
// ---------------------------------------------------------------------------

__global__ void hist_kernel(const int* __restrict__ dst, int E,
                            int* __restrict__ bucketCnt, int NB) {
    __shared__ int h[1024];
    int t = threadIdx.x;
    for (int i = t; i < 1024; i += 256) h[i] = 0;
    __syncthreads();
    for (int e = blockIdx.x * 256 + t; e < E; e += gridDim.x * 256)
        atomicAdd(&h[dst[e] >> BUCKET_SHIFT], 1);
    __syncthreads();
    for (int i = t; i < NB; i += 256)
        if (h[i]) atomicAdd(&bucketCnt[i], h[i]);   // no return use -> pipelined
}

__global__ void bucket_scan(const int* __restrict__ bucketCnt,
                            int* __restrict__ bucketBase, int* __restrict__ bucketCur,
                            int NB, int E) {
    __shared__ int sm[1024];
    int t = threadIdx.x;
    int v = (t < NB) ? bucketCnt[t] : 0;
    sm[t] = v;
    __syncthreads();
    for (int off = 1; off < 1024; off <<= 1) {
        int add = (t >= off) ? sm[t - off] : 0;
        __syncthreads();
        sm[t] += add;
        __syncthreads();
    }
    if (t < NB) {
        bucketBase[t] = sm[t] - v;
        bucketCur[t] = sm[t] - v;
    }
    if (t == 0) bucketBase[NB] = E;
}

// Two-level scatter: per-chunk LDS histogram, one returning atomic per
// (block,bucket), then contiguous placement via LDS cursors.
__global__ void scatter_kernel(const int* __restrict__ src, const int* __restrict__ dst,
                               int E, int* __restrict__ bucketCur, unsigned* __restrict__ rec) {
    __shared__ int hist[1024];
    __shared__ int base[1024];
    int t = threadIdx.x;
    int e0 = blockIdx.x * SCHUNK;
    int e1 = MIN(E, e0 + SCHUNK);
    for (int i = t; i < 1024; i += 256) hist[i] = 0;
    __syncthreads();
    for (int e = e0 + t; e < e1; e += 256)
        atomicAdd(&hist[dst[e] >> BUCKET_SHIFT], 1);
    __syncthreads();
    for (int i = t; i < 1024; i += 256) {
        int c = hist[i];
        base[i] = c ? atomicAdd(&bucketCur[i], c) : 0;
        hist[i] = 0;                                      // reuse as local cursor
    }
    __syncthreads();
    for (int e = e0 + t; e < e1; e += 256) {
        int d = dst[e];
        int b = d >> BUCKET_SHIFT;
        int pos = base[b] + atomicAdd(&hist[b], 1);       // LDS atomic, cheap
        rec[pos] = (unsigned)src[e] | ((unsigned)(d & (BUCKET_SIZE - 1)) << 16);
    }
}

__global__ void bucket_build(const unsigned* __restrict__ rec, const int* __restrict__ bucketBase,
                             int* __restrict__ rowptr, int* __restrict__ csr_src,
                             float* __restrict__ dinv, int N, int E) {
    __shared__ int lcnt[256];
    __shared__ int sm[256];
    __shared__ int lcur[64];
    int b = blockIdx.x;
    int t = threadIdx.x;
    int beg = bucketBase[b], end = bucketBase[b + 1];
    lcnt[t] = 0;
    __syncthreads();
    for (int i = beg + t; i < end; i += 256)
        atomicAdd(&lcnt[rec[i] >> 16], 1);
    __syncthreads();
    int v = lcnt[t];
    sm[t] = v;
    __syncthreads();
    for (int off = 1; off < 256; off <<= 1) {
        int add = (t >= off) ? sm[t - off] : 0;
        __syncthreads();
        sm[t] += add;
        __syncthreads();
    }
    int excl = sm[t] - v;
    if (t < BUCKET_SIZE) {
        int node = b * BUCKET_SIZE + t;
        if (node < N) {
            rowptr[node] = beg + excl;
            dinv[node] = rsqrtf((float)(v + 1));   // self loop -> deg >= 1
        }
        lcur[t] = beg + excl;
    }
    __syncthreads();
    for (int i = beg + t; i < end; i += 256) {
        unsigned r = rec[i];
        int pos = atomicAdd(&lcur[r >> 16], 1);
        csr_src[pos] = (int)(r & 0xFFFFu);
    }
    if (b == 0 && t == 0) rowptr[N] = E;
}

// ---------------------------------------------------------------------------
// Aggregation over f16 H: X[node] = relu( di*( di*H[node] + sum dinv[s]*H[s] ) )
// 1 wave per node; 64-edge batches via shfl; 16 independent gathers in flight.
// ---------------------------------------------------------------------------

__global__ void agg_kernel(const half2_t* __restrict__ Hb, const float* __restrict__ dinv,
                           const int* __restrict__ rowptr, const int* __restrict__ csr_src,
                           half2_t* __restrict__ X, int N) {
    int node = blockIdx.x * 4 + (threadIdx.x >> 6);
    int t = threadIdx.x & 63;
    if (node >= N) return;
    float di = dinv[node];
    half2_t hu = Hb[(size_t)node * 64 + t];
    float2 acc;
    acc.x = (float)hu.x * di;
    acc.y = (float)hu.y * di;
    int beg = rowptr[node];
    int end = rowptr[node + 1];

    for (int base = beg; base < end; base += 64) {
        int idx = base + t;
        bool valid = idx < end;
        int s_lane = valid ? csr_src[idx] : node;    // safe address for pads
        float w_lane = valid ? dinv[s_lane] : 0.0f;  // zero weight for pads
        int m = end - base;
        if (m > 64) m = 64;
        int mm = (m + 15) & ~15;                     // pads contribute 0
        for (int j = 0; j < mm; j += 16) {
            half2_t u[16];
            float w[16];
#pragma unroll
            for (int k = 0; k < 16; ++k) {
                int s = __shfl(s_lane, j + k);
                w[k] = __shfl(w_lane, j + k);
                u[k] = Hb[(size_t)s * 64 + t];
            }
#pragma unroll
            for (int k = 0; k < 16; ++k) {
                acc.x = fmaf((float)u[k].x, w[k], acc.x);
                acc.y = fmaf((float)u[k].y, w[k], acc.y);
            }
        }
    }
    half2_t o;
    o.x = (_Float16)fmaxf(acc.x * di, 0.0f);
    o.y = (_Float16)fmaxf(acc.y * di, 0.0f);
    X[(size_t)node * 64 + t] = o;
}

// ---------------------------------------------------------------------------
// MFMA f16 GEMM, K=128, BM=64, 256 threads (4 waves). W staged fp32->f16 in
// LDS; A-fragments loaded directly from global (each element once, L2-hot).
// A: lane reads A[m=lane&15][k=(lane>>4)*8+ks*32 ..+7]; C/D: col=lane&15,
// row=(lane>>4)*4+reg.
// ---------------------------------------------------------------------------

template <int BN, bool A_F16, bool RELU, bool BIAS, bool ACCUM, bool F16OUT>
__global__ __launch_bounds__(256)
void mfma_gemm(const void* __restrict__ Av,
               const float* __restrict__ W, int ldw,
               const float* __restrict__ bias,
               void* __restrict__ Cv, int ldc, int M) {
    constexpr int NT = BN / 16;
    __shared__ __align__(16) _Float16 Ws[BN][WPAD];

    int tid = threadIdx.x;
    int rowBase = blockIdx.x * 64;

#pragma unroll
    for (int i = tid; i < BN * 32; i += 256) {
        int n = i >> 5, c4 = (i & 31) * 4;
        float4 v = *(const float4*)(W + (size_t)n * ldw + c4);
        half4_t h = {(_Float16)v.x, (_Float16)v.y, (_Float16)v.z, (_Float16)v.w};
        *(half4_t*)(&Ws[n][c4]) = h;
    }
    __syncthreads();

    int w = tid >> 6;
    int lane = tid & 63;
    int lrow = lane & 15;
    int quad = lane >> 4;
    int kq = quad * 8;
    int grow = rowBase + w * 16 + lrow;
    bool rok = grow < M;

    floatx4 acc[NT];
#pragma unroll
    for (int nt = 0; nt < NT; ++nt) acc[nt] = (floatx4){0.f, 0.f, 0.f, 0.f};

#pragma unroll
    for (int ks = 0; ks < 4; ++ks) {
        int kk = ks * 32 + kq;
        half8_t a = {0, 0, 0, 0, 0, 0, 0, 0};
        if (rok) {
            if (A_F16) {
                a = *(const half8_t*)((const _Float16*)Av + (size_t)grow * 128 + kk);
            } else {
                const float* A = (const float*)Av;
                float4 v0 = *(const float4*)(A + (size_t)grow * 128 + kk);
                float4 v1 = *(const float4*)(A + (size_t)grow * 128 + kk + 4);
                a = (half8_t){(_Float16)v0.x, (_Float16)v0.y, (_Float16)v0.z, (_Float16)v0.w,
                              (_Float16)v1.x, (_Float16)v1.y, (_Float16)v1.z, (_Float16)v1.w};
            }
        }
#pragma unroll
        for (int nt = 0; nt < NT; ++nt) {
            half8_t b = *(const half8_t*)(&Ws[nt * 16 + lrow][kk]);
            acc[nt] = __builtin_amdgcn_mfma_f32_16x16x32_f16(a, b, acc[nt], 0, 0, 0);
        }
    }

#pragma unroll
    for (int nt = 0; nt < NT; ++nt) {
        int col = nt * 16 + lrow;
        float bv = BIAS ? bias[col] : 0.0f;
#pragma unroll
        for (int reg = 0; reg < 4; ++reg) {
            int gr = rowBase + w * 16 + quad * 4 + reg;
            if (gr < M) {
                float v = acc[nt][reg] + bv;
                if (RELU) v = fmaxf(v, 0.0f);
                if (F16OUT) {
                    _Float16* C = (_Float16*)Cv;
                    C[(size_t)gr * ldc + col] = (_Float16)v;
                } else {
                    float* C = (float*)Cv;
                    if (ACCUM) v += C[(size_t)gr * ldc + col];
                    C[(size_t)gr * ldc + col] = v;
                }
            }
        }
    }
}

// ---------------------------------------------------------------------------
// Fused conv-GEMM + out-slice GEMM: reads A (f16) once, computes
//   H[m][0..127]   = A @ W1^T + bc        (f16 out)
//   out[m][0..63] (+)= A @ W2^T (+b_out)  (fp32, FIRST: overwrite w/ bias)
// ---------------------------------------------------------------------------

template <bool FIRST>
__global__ __launch_bounds__(256)
void mfma_gemm_fused(const _Float16* __restrict__ A,
                     const float* __restrict__ W1,           // [128][128]
                     const float* __restrict__ bc,
                     _Float16* __restrict__ H,
                     const float* __restrict__ W2, int ldw2, // [64][ldw2] slice
                     const float* __restrict__ b_out,
                     float* __restrict__ out, int M) {
    __shared__ __align__(16) _Float16 Ws[192][WPAD];   // rows 0..127=W1, 128..191=W2

    int tid = threadIdx.x;
    int rowBase = blockIdx.x * 64;

#pragma unroll
    for (int i = tid; i < 128 * 32; i += 256) {
        int n = i >> 5, c4 = (i & 31) * 4;
        float4 v = *(const float4*)(W1 + (size_t)n * 128 + c4);
        half4_t h = {(_Float16)v.x, (_Float16)v.y, (_Float16)v.z, (_Float16)v.w};
        *(half4_t*)(&Ws[n][c4]) = h;
    }
#pragma unroll
    for (int i = tid; i < 64 * 32; i += 256) {
        int n = i >> 5, c4 = (i & 31) * 4;
        float4 v = *(const float4*)(W2 + (size_t)n * ldw2 + c4);
        half4_t h = {(_Float16)v.x, (_Float16)v.y, (_Float16)v.z, (_Float16)v.w};
        *(half4_t*)(&Ws[128 + n][c4]) = h;
    }
    __syncthreads();

    int w = tid >> 6;
    int lane = tid & 63;
    int lrow = lane & 15;
    int quad = lane >> 4;
    int kq = quad * 8;
    int grow = rowBase + w * 16 + lrow;
    bool rok = grow < M;

    floatx4 acc1[8], acc2[4];
#pragma unroll
    for (int nt = 0; nt < 8; ++nt) acc1[nt] = (floatx4){0.f, 0.f, 0.f, 0.f};
#pragma unroll
    for (int nt = 0; nt < 4; ++nt) acc2[nt] = (floatx4){0.f, 0.f, 0.f, 0.f};

#pragma unroll
    for (int ks = 0; ks < 4; ++ks) {
        int kk = ks * 32 + kq;
        half8_t a = {0, 0, 0, 0, 0, 0, 0, 0};
        if (rok) a = *(const half8_t*)(A + (size_t)grow * 128 + kk);
#pragma unroll
        for (int nt = 0; nt < 8; ++nt) {
            half8_t b = *(const half8_t*)(&Ws[nt * 16 + lrow][kk]);
            acc1[nt] = __builtin_amdgcn_mfma_f32_16x16x32_f16(a, b, acc1[nt], 0, 0, 0);
        }
#pragma unroll
        for (int nt = 0; nt < 4; ++nt) {
            half8_t b = *(const half8_t*)(&Ws[128 + nt * 16 + lrow][kk]);
            acc2[nt] = __builtin_amdgcn_mfma_f32_16x16x32_f16(a, b, acc2[nt], 0, 0, 0);
        }
    }

#pragma unroll
    for (int nt = 0; nt < 8; ++nt) {
        int col = nt * 16 + lrow;
        float bv = bc[col];
#pragma unroll
        for (int reg = 0; reg < 4; ++reg) {
            int gr = rowBase + w * 16 + quad * 4 + reg;
            if (gr < M) H[(size_t)gr * 128 + col] = (_Float16)(acc1[nt][reg] + bv);
        }
    }
#pragma unroll
    for (int nt = 0; nt < 4; ++nt) {
        int col = nt * 16 + lrow;
        float bv = FIRST ? b_out[col] : 0.0f;
#pragma unroll
        for (int reg = 0; reg < 4; ++reg) {
            int gr = rowBase + w * 16 + quad * 4 + reg;
            if (gr < M) {
                float v = acc2[nt][reg] + bv;
                if (!FIRST) v += out[(size_t)gr * 64 + col];
                out[(size_t)gr * 64 + col] = v;
            }
        }
    }
}

// ---------------------------------------------------------------------------
// launch
// ---------------------------------------------------------------------------

extern "C" void kernel_launch(void* const* d_in, const int* in_sizes, int n_in,
                              void* d_out, int out_size, void* d_ws, size_t ws_size,
                              hipStream_t stream) {
    const float* x     = (const float*)d_in[0];
    const int*   ei    = (const int*)d_in[1];
    const float* W_in  = (const float*)d_in[2];
    const float* b_in  = (const float*)d_in[3];
    const float* Wc    = (const float*)d_in[4];
    const float* bc    = (const float*)d_in[5];
    const float* W_out = (const float*)d_in[6];
    const float* b_out = (const float*)d_in[7];
    float* out = (float*)d_out;

    const int HID = 128;
    const int N = in_sizes[0] / HID;   // 50000
    const int E = in_sizes[1] / 2;     // 800000
    const int* src = ei;
    const int* dst = ei + E;
    const int NB = (N + BUCKET_SIZE - 1) >> BUCKET_SHIFT;   // 782

    char* ws = (char*)d_ws;
    size_t off = 0;
    auto carve = [&](size_t bytes) {
        void* p = ws + off;
        off += (bytes + 255) & ~(size_t)255;
        return p;
    };
    float* dinv      = (float*)carve((size_t)N * 4);
    int*   rowptr    = (int*)carve((size_t)(N + 1) * 4);
    int*   csr_src   = (int*)carve((size_t)E * 4);
    unsigned* rec    = (unsigned*)carve((size_t)E * 4);
    int*   bucketCnt = (int*)carve((size_t)1024 * 4);
    int*   bucketBase= (int*)carve((size_t)1025 * 4);
    int*   bucketCur = (int*)carve((size_t)1024 * 4);
    _Float16* bufA   = (_Float16*)carve((size_t)N * HID * 2);
    _Float16* bufH   = (_Float16*)carve((size_t)N * HID * 2);
    (void)ws_size;

    // ---- bucketed CSR + norm build ----
    hipMemsetAsync(bucketCnt, 0, (size_t)1024 * 4, stream);
    hist_kernel<<<512, 256, 0, stream>>>(dst, E, bucketCnt, NB);
    bucket_scan<<<1, 1024, 0, stream>>>(bucketCnt, bucketBase, bucketCur, NB, E);
    scatter_kernel<<<(E + SCHUNK - 1) / SCHUNK, 256, 0, stream>>>(src, dst, E, bucketCur, rec);
    bucket_build<<<NB, 256, 0, stream>>>(rec, bucketBase, rowptr, csr_src, dinv, N, E);

    int gemm_blocks = (N + 63) / 64;
    dim3 agg_grid((N + 3) / 4);

    // ---- input projection: bufA = f16( relu(x @ W_in^T + b_in) ) ----
    mfma_gemm<128, false, true, true, false, true>
        <<<gemm_blocks, 256, 0, stream>>>(x, W_in, HID, b_in, bufA, HID, N);

    // ---- layer 0 conv ----
    mfma_gemm<128, true, false, true, false, true>
        <<<gemm_blocks, 256, 0, stream>>>(bufA, Wc, HID, bc, bufH, HID, N);
    agg_kernel<<<agg_grid, 256, 0, stream>>>((const half2_t*)bufH, dinv, rowptr,
                                             csr_src, (half2_t*)bufA, N);

    // ---- layers 1..3: fused [conv_l | out-slice_{l-1}] then agg ----
    for (int l = 1; l < 4; ++l) {
        if (l == 1) {
            mfma_gemm_fused<true><<<gemm_blocks, 256, 0, stream>>>(
                bufA, Wc + (size_t)l * HID * HID, bc + (size_t)l * HID, bufH,
                W_out + (size_t)(l - 1) * HID, 512, b_out, out, N);
        } else {
            mfma_gemm_fused<false><<<gemm_blocks, 256, 0, stream>>>(
                bufA, Wc + (size_t)l * HID * HID, bc + (size_t)l * HID, bufH,
                W_out + (size_t)(l - 1) * HID, 512, nullptr, out, N);
        }
        agg_kernel<<<agg_grid, 256, 0, stream>>>((const half2_t*)bufH, dinv, rowptr,
                                                 csr_src, (half2_t*)bufA, N);
    }

    // ---- final out slice (l=3): out += bufA @ W_out[:, 384:512]^T ----
    mfma_gemm<64, true, false, false, true, false>
        <<<gemm_blocks, 256, 0, stream>>>(bufA, W_out + (size_t)3 * HID, 512,
                                          nullptr, out, 64, N);
}